// Round 1
// baseline (400.179 us; speedup 1.0000x reference)
//
#include <hip/hip_runtime.h>
#include <math.h>

// ---------------------------------------------------------------------------
// GCN 2-layer forward on MI355X.
// Pipeline per call (workspace is re-poisoned each call, so everything is
// rebuilt): detect int64/int32 edge dtype -> init -> weighted-degree +
// count histogram -> dinv=1/sqrt(deg) -> 3-kernel exclusive scan -> CSR fill
// (src, norm sorted by dst) -> GEMM1 -> aggregate+self+bias+ReLU ->
// GEMM2 -> aggregate+self+bias -> d_out.
// ---------------------------------------------------------------------------

// --- dtype detect: flag=1 if edge_index is int64 (all sampled high words 0) ---
__global__ __launch_bounds__(256) void k_detect(const int* __restrict__ ei,
                                                int* __restrict__ flagp, int E) {
  __shared__ int sm[256];
  int t = threadIdx.x;
  int v = 0;
#pragma unroll
  for (int j = 0; j < 8; ++j) {
    int e = t * 8 + j;           // e < 2048, safely inside both layouts
    if (2 * e + 1 < 2 * E) v |= ei[2 * e + 1];
  }
  sm[t] = v;
  __syncthreads();
  for (int off = 128; off > 0; off >>= 1) {
    if (t < off) sm[t] |= sm[t + off];
    __syncthreads();
  }
  if (t == 0) flagp[0] = (sm[0] == 0) ? 1 : 0;
}

__global__ __launch_bounds__(256) void k_init(float* __restrict__ deg,
                                              int* __restrict__ cnt,
                                              int* __restrict__ cursor, int N) {
  int i = blockIdx.x * 256 + threadIdx.x;
  if (i < N) { deg[i] = 1.0f; cnt[i] = 0; cursor[i] = 0; }
}

// weighted degree (by dst) + incoming-edge count histogram
__global__ __launch_bounds__(256) void k_hist(const int* __restrict__ ei,
                                              const float* __restrict__ ew,
                                              float* __restrict__ deg,
                                              int* __restrict__ cnt, int E,
                                              const int* __restrict__ flagp) {
  int e = blockIdx.x * 256 + threadIdx.x;
  if (e >= E) return;
  int is64 = flagp[0];
  int d = is64 ? ei[2 * E + 2 * e] : ei[E + e];
  atomicAdd(&deg[d], ew[e]);
  atomicAdd(&cnt[d], 1);
}

__global__ __launch_bounds__(256) void k_dinv(float* __restrict__ degdinv, int N) {
  int i = blockIdx.x * 256 + threadIdx.x;
  if (i < N) degdinv[i] = 1.0f / sqrtf(degdinv[i]);  // deg >= 1 always
}

// --- 3-kernel exclusive scan over cnt[0..N) -> row_start[0..N] ---
__global__ __launch_bounds__(256) void k_scan1(const int* __restrict__ cnt,
                                               int* __restrict__ bsum, int N) {
  __shared__ int sm[256];
  int t = threadIdx.x;
  int i = blockIdx.x * 256 + t;
  sm[t] = (i < N) ? cnt[i] : 0;
  __syncthreads();
  for (int off = 128; off > 0; off >>= 1) {
    if (t < off) sm[t] += sm[t + off];
    __syncthreads();
  }
  if (t == 0) bsum[blockIdx.x] = sm[0];
}

__global__ __launch_bounds__(256) void k_scan2(int* __restrict__ bsum,
                                               int* __restrict__ row_start,
                                               int NB, int N, int E) {
  __shared__ int sm[256];
  int t = threadIdx.x;
  int v = (t < NB) ? bsum[t] : 0;
  sm[t] = v;
  __syncthreads();
  for (int off = 1; off < 256; off <<= 1) {
    int add = (t >= off) ? sm[t - off] : 0;
    __syncthreads();
    sm[t] += add;
    __syncthreads();
  }
  if (t < NB) bsum[t] = sm[t] - v;  // exclusive block offsets
  if (t == 0) row_start[N] = E;
}

__global__ __launch_bounds__(256) void k_scan3(const int* __restrict__ cnt,
                                               const int* __restrict__ bsum,
                                               int* __restrict__ row_start, int N) {
  __shared__ int sm[256];
  int t = threadIdx.x;
  int i = blockIdx.x * 256 + t;
  int v = (i < N) ? cnt[i] : 0;
  sm[t] = v;
  __syncthreads();
  for (int off = 1; off < 256; off <<= 1) {
    int add = (t >= off) ? sm[t - off] : 0;
    __syncthreads();
    sm[t] += add;
    __syncthreads();
  }
  if (i < N) row_start[i] = sm[t] - v + bsum[blockIdx.x];
}

// CSR fill: (src, norm) pairs grouped by dst
__global__ __launch_bounds__(256) void k_fill(const int* __restrict__ ei,
                                              const float* __restrict__ ew,
                                              const float* __restrict__ dinv,
                                              const int* __restrict__ row_start,
                                              int* __restrict__ cursor,
                                              int* __restrict__ csr_src,
                                              float* __restrict__ csr_norm, int E,
                                              const int* __restrict__ flagp) {
  int e = blockIdx.x * 256 + threadIdx.x;
  if (e >= E) return;
  int is64 = flagp[0];
  int s, d;
  if (is64) { s = ei[2 * e]; d = ei[2 * E + 2 * e]; }
  else      { s = ei[e];     d = ei[E + e]; }
  float nw = dinv[s] * ew[e] * dinv[d];
  int pos = row_start[d] + atomicAdd(&cursor[d], 1);
  csr_src[pos] = s;
  csr_norm[pos] = nw;
}

// --- fp32 register-tiled GEMM: Y[M,NC] = X[M,128] @ W[128,NC] ---
// 64 rows per block; each thread: 4 cols x (64/RS) rows, float4 loads.
template <int NC>
__global__ __launch_bounds__(256) void gemm_kernel(const float* __restrict__ X,
                                                   const float* __restrict__ W,
                                                   float* __restrict__ Y, int M) {
  constexpr int K = 128;
  constexpr int CG = NC / 4;    // col groups: 32 (NC=128) or 16 (NC=64)
  constexpr int RS = 256 / CG;  // row subs: 8 or 16
  constexpr int RI = 64 / RS;   // rows per thread: 8 or 4
  int t = threadIdx.x;
  int cg = t % CG;
  int rs = t / CG;
  int rbase = blockIdx.x * 64;

  float4 acc[RI];
#pragma unroll
  for (int i = 0; i < RI; ++i) acc[i] = make_float4(0.f, 0.f, 0.f, 0.f);

  int rows[RI];
#pragma unroll
  for (int i = 0; i < RI; ++i) {
    int r = rbase + rs + RS * i;
    rows[i] = (r < M) ? r : (M - 1);  // clamp loads, guard stores
  }

  for (int k0 = 0; k0 < K; k0 += 4) {
    float4 w[4];
#pragma unroll
    for (int j = 0; j < 4; ++j)
      w[j] = *(const float4*)&W[(k0 + j) * NC + 4 * cg];
#pragma unroll
    for (int i = 0; i < RI; ++i) {
      float4 xq = *(const float4*)&X[rows[i] * K + k0];
      acc[i].x += xq.x * w[0].x + xq.y * w[1].x + xq.z * w[2].x + xq.w * w[3].x;
      acc[i].y += xq.x * w[0].y + xq.y * w[1].y + xq.z * w[2].y + xq.w * w[3].y;
      acc[i].z += xq.x * w[0].z + xq.y * w[1].z + xq.z * w[2].z + xq.w * w[3].z;
      acc[i].w += xq.x * w[0].w + xq.y * w[1].w + xq.z * w[2].w + xq.w * w[3].w;
    }
  }

#pragma unroll
  for (int i = 0; i < RI; ++i) {
    int r = rbase + rs + RS * i;
    if (r < M) *(float4*)&Y[r * NC + 4 * cg] = acc[i];
  }
}

// --- gather-style aggregation (atomic-free), fused self-loop + bias (+ReLU) ---
// LPN = NC/4 lanes per node, each lane owns a float4 of the feature dim.
template <int NC, bool RELU>
__global__ __launch_bounds__(256) void agg_kernel(const float* __restrict__ H,
                                                  const int* __restrict__ row_start,
                                                  const int* __restrict__ csr_src,
                                                  const float* __restrict__ csr_norm,
                                                  const float* __restrict__ dinv,
                                                  const float* __restrict__ bias,
                                                  float* __restrict__ OUT, int N) {
  constexpr int LPN = NC / 4;    // 32 or 16
  constexpr int NPB = 256 / LPN; // 8 or 16
  int t = threadIdx.x;
  int lane = t % LPN;
  int n = blockIdx.x * NPB + t / LPN;
  if (n >= N) return;

  int s0 = row_start[n];
  int s1 = row_start[n + 1];
  float4 acc = make_float4(0.f, 0.f, 0.f, 0.f);
  for (int j = s0; j < s1; ++j) {
    int s = csr_src[j];
    float w = csr_norm[j];
    float4 h = *(const float4*)&H[s * NC + 4 * lane];
    acc.x += w * h.x; acc.y += w * h.y; acc.z += w * h.z; acc.w += w * h.w;
  }
  float di = dinv[n];
  float sw = di * di;
  float4 hs = *(const float4*)&H[n * NC + 4 * lane];
  float4 b  = *(const float4*)&bias[4 * lane];
  float4 o;
  o.x = acc.x + sw * hs.x + b.x;
  o.y = acc.y + sw * hs.y + b.y;
  o.z = acc.z + sw * hs.z + b.z;
  o.w = acc.w + sw * hs.w + b.w;
  if (RELU) {
    o.x = fmaxf(o.x, 0.f); o.y = fmaxf(o.y, 0.f);
    o.z = fmaxf(o.z, 0.f); o.w = fmaxf(o.w, 0.f);
  }
  *(float4*)&OUT[n * NC + 4 * lane] = o;
}

extern "C" void kernel_launch(void* const* d_in, const int* in_sizes, int n_in,
                              void* d_out, int out_size, void* d_ws, size_t ws_size,
                              hipStream_t stream) {
  const float* x  = (const float*)d_in[0];
  const int*   ei = (const int*)d_in[1];
  const float* ew = (const float*)d_in[2];
  const float* W1 = (const float*)d_in[3];
  const float* b1 = (const float*)d_in[4];
  const float* W2 = (const float*)d_in[5];
  const float* b2 = (const float*)d_in[6];
  float* out = (float*)d_out;

  const int IN_D = 128, HID = 128, OUT_D = 64;
  const int N = in_sizes[0] / IN_D;   // 50000
  const int E = in_sizes[2];          // 800000

  char* ws = (char*)d_ws;
  size_t off = 0;
  auto take = [&](size_t bytes) -> void* {
    void* p = ws + off;
    off += (bytes + 255) & ~(size_t)255;
    return p;
  };
  float* dinv      = (float*)take((size_t)N * 4);      // deg then dinv in-place
  int*   cnt       = (int*)take((size_t)N * 4);
  int*   cursor    = (int*)take((size_t)N * 4);
  int*   row_start = (int*)take((size_t)(N + 1) * 4);
  int*   bsum      = (int*)take(256 * 4);
  int*   flag      = (int*)take(256);
  int*   csr_src   = (int*)take((size_t)E * 4);
  float* csr_norm  = (float*)take((size_t)E * 4);
  float* h1        = (float*)take((size_t)N * HID * 4);
  float* h2        = (float*)take((size_t)N * HID * 4);
  float* h3        = (float*)take((size_t)N * OUT_D * 4);

  int nb_n = (N + 255) / 256;  // 196
  int nb_e = (E + 255) / 256;  // 3125
  int nb_g = (N + 63) / 64;    // 782

  hipLaunchKernelGGL(k_detect, dim3(1), dim3(256), 0, stream, ei, flag, E);
  hipLaunchKernelGGL(k_init, dim3(nb_n), dim3(256), 0, stream, dinv, cnt, cursor, N);
  hipLaunchKernelGGL(k_hist, dim3(nb_e), dim3(256), 0, stream, ei, ew, dinv, cnt, E, flag);
  hipLaunchKernelGGL(k_dinv, dim3(nb_n), dim3(256), 0, stream, dinv, N);
  hipLaunchKernelGGL(k_scan1, dim3(nb_n), dim3(256), 0, stream, cnt, bsum, N);
  hipLaunchKernelGGL(k_scan2, dim3(1), dim3(256), 0, stream, bsum, row_start, nb_n, N, E);
  hipLaunchKernelGGL(k_scan3, dim3(nb_n), dim3(256), 0, stream, cnt, bsum, row_start, N);
  hipLaunchKernelGGL(k_fill, dim3(nb_e), dim3(256), 0, stream, ei, ew, dinv, row_start,
                     cursor, csr_src, csr_norm, E, flag);
  hipLaunchKernelGGL((gemm_kernel<128>), dim3(nb_g), dim3(256), 0, stream, x, W1, h1, N);
  hipLaunchKernelGGL((agg_kernel<128, true>), dim3((N + 7) / 8), dim3(256), 0, stream,
                     h1, row_start, csr_src, csr_norm, dinv, b1, h2, N);
  hipLaunchKernelGGL((gemm_kernel<64>), dim3(nb_g), dim3(256), 0, stream, h2, W2, h3, N);
  hipLaunchKernelGGL((agg_kernel<64, false>), dim3((N + 15) / 16), dim3(256), 0, stream,
                     h3, row_start, csr_src, csr_norm, dinv, b2, out, N);
}

// Round 2
// 334.465 us; speedup vs baseline: 1.1965x; 1.1965x over previous
//
#include <hip/hip_runtime.h>
#include <math.h>

// ---------------------------------------------------------------------------
// GCN 2-layer forward on MI355X.
// Round 2: single packed 64-bit atomic per edge replaces 3 scattered 32-bit
// atomics (deg-add, cnt-add, cursor-add). Packed layout:
//   bits [40:63] = incoming-edge count
//   bits [ 0:39] = sum of edge weights, fixed-point scale 2^-24
// The atomicAdd return value's high bits give this edge's rank within its
// dst row -> CSR fill needs no atomics. Fill writes one int2 {src, norm}.
// ---------------------------------------------------------------------------

#define WFIX_SCALE 16777216.0f  // 2^24
#define WFIX_MASK  0xFFFFFFFFFFULL

// --- dtype detect: flag=1 if edge_index is int64 (all sampled high words 0) ---
__global__ __launch_bounds__(256) void k_detect(const int* __restrict__ ei,
                                                int* __restrict__ flagp, int E) {
  __shared__ int sm[256];
  int t = threadIdx.x;
  int v = 0;
#pragma unroll
  for (int j = 0; j < 8; ++j) {
    int e = t * 8 + j;           // e < 2048, safely inside both layouts
    if (2 * e + 1 < 2 * E) v |= ei[2 * e + 1];
  }
  sm[t] = v;
  __syncthreads();
  for (int off = 128; off > 0; off >>= 1) {
    if (t < off) sm[t] |= sm[t + off];
    __syncthreads();
  }
  if (t == 0) flagp[0] = (sm[0] == 0) ? 1 : 0;
}

__global__ __launch_bounds__(256) void k_init(unsigned long long* __restrict__ packed,
                                              int N) {
  int i = blockIdx.x * 256 + threadIdx.x;
  if (i < N) packed[i] = 0ULL;
}

// one packed 64-bit atomic per edge; returned old value -> rank within dst row
__global__ __launch_bounds__(256) void k_hist2(const int* __restrict__ ei,
                                               const float* __restrict__ ew,
                                               unsigned long long* __restrict__ packed,
                                               unsigned short* __restrict__ rank,
                                               int E, const int* __restrict__ flagp) {
  int e = blockIdx.x * 256 + threadIdx.x;
  if (e >= E) return;
  int is64 = flagp[0];
  int d = is64 ? ei[2 * E + 2 * e] : ei[E + e];
  unsigned long long wfix = (unsigned long long)(ew[e] * WFIX_SCALE + 0.5f);
  unsigned long long old = atomicAdd(&packed[d], wfix | (1ULL << 40));
  rank[e] = (unsigned short)(old >> 40);
}

// unpack: dinv = rsqrt(1 + wsum), cnt; and block-sum cnt for the scan
__global__ __launch_bounds__(256) void k_dinv_scan1(
    const unsigned long long* __restrict__ packed, float* __restrict__ dinv,
    int* __restrict__ cnt, int* __restrict__ bsum, int N) {
  __shared__ int sm[256];
  int t = threadIdx.x;
  int i = blockIdx.x * 256 + t;
  int c = 0;
  if (i < N) {
    unsigned long long p = packed[i];
    c = (int)(p >> 40);
    float deg = 1.0f + (float)(p & WFIX_MASK) * (1.0f / WFIX_SCALE);
    dinv[i] = rsqrtf(deg);
    cnt[i] = c;
  }
  sm[t] = c;
  __syncthreads();
  for (int off = 128; off > 0; off >>= 1) {
    if (t < off) sm[t] += sm[t + off];
    __syncthreads();
  }
  if (t == 0) bsum[blockIdx.x] = sm[0];
}

__global__ __launch_bounds__(256) void k_scan2(int* __restrict__ bsum,
                                               int* __restrict__ row_start,
                                               int NB, int N, int E) {
  __shared__ int sm[256];
  int t = threadIdx.x;
  int v = (t < NB) ? bsum[t] : 0;
  sm[t] = v;
  __syncthreads();
  for (int off = 1; off < 256; off <<= 1) {
    int add = (t >= off) ? sm[t - off] : 0;
    __syncthreads();
    sm[t] += add;
    __syncthreads();
  }
  if (t < NB) bsum[t] = sm[t] - v;  // exclusive block offsets
  if (t == 0) row_start[N] = E;
}

__global__ __launch_bounds__(256) void k_scan3(const int* __restrict__ cnt,
                                               const int* __restrict__ bsum,
                                               int* __restrict__ row_start, int N) {
  __shared__ int sm[256];
  int t = threadIdx.x;
  int i = blockIdx.x * 256 + t;
  int v = (i < N) ? cnt[i] : 0;
  sm[t] = v;
  __syncthreads();
  for (int off = 1; off < 256; off <<= 1) {
    int add = (t >= off) ? sm[t - off] : 0;
    __syncthreads();
    sm[t] += add;
    __syncthreads();
  }
  if (i < N) row_start[i] = sm[t] - v + bsum[blockIdx.x];
}

// CSR fill, atomic-free: pos = row_start[dst] + rank[e]; one packed int2 store
__global__ __launch_bounds__(256) void k_fill2(const int* __restrict__ ei,
                                               const float* __restrict__ ew,
                                               const float* __restrict__ dinv,
                                               const int* __restrict__ row_start,
                                               const unsigned short* __restrict__ rank,
                                               int2* __restrict__ csr, int E,
                                               const int* __restrict__ flagp) {
  int e = blockIdx.x * 256 + threadIdx.x;
  if (e >= E) return;
  int is64 = flagp[0];
  int s, d;
  if (is64) { s = ei[2 * e]; d = ei[2 * E + 2 * e]; }
  else      { s = ei[e];     d = ei[E + e]; }
  float nw = dinv[s] * ew[e] * dinv[d];
  int pos = row_start[d] + (int)rank[e];
  csr[pos] = make_int2(s, __float_as_int(nw));
}

// --- fp32 register-tiled GEMM: Y[M,NC] = X[M,128] @ W[128,NC] ---
template <int NC>
__global__ __launch_bounds__(256) void gemm_kernel(const float* __restrict__ X,
                                                   const float* __restrict__ W,
                                                   float* __restrict__ Y, int M) {
  constexpr int K = 128;
  constexpr int CG = NC / 4;    // col groups: 32 (NC=128) or 16 (NC=64)
  constexpr int RS = 256 / CG;  // row subs: 8 or 16
  constexpr int RI = 64 / RS;   // rows per thread: 8 or 4
  int t = threadIdx.x;
  int cg = t % CG;
  int rs = t / CG;
  int rbase = blockIdx.x * 64;

  float4 acc[RI];
#pragma unroll
  for (int i = 0; i < RI; ++i) acc[i] = make_float4(0.f, 0.f, 0.f, 0.f);

  int rows[RI];
#pragma unroll
  for (int i = 0; i < RI; ++i) {
    int r = rbase + rs + RS * i;
    rows[i] = (r < M) ? r : (M - 1);  // clamp loads, guard stores
  }

  for (int k0 = 0; k0 < K; k0 += 4) {
    float4 w[4];
#pragma unroll
    for (int j = 0; j < 4; ++j)
      w[j] = *(const float4*)&W[(k0 + j) * NC + 4 * cg];
#pragma unroll
    for (int i = 0; i < RI; ++i) {
      float4 xq = *(const float4*)&X[rows[i] * K + k0];
      acc[i].x += xq.x * w[0].x + xq.y * w[1].x + xq.z * w[2].x + xq.w * w[3].x;
      acc[i].y += xq.x * w[0].y + xq.y * w[1].y + xq.z * w[2].y + xq.w * w[3].y;
      acc[i].z += xq.x * w[0].z + xq.y * w[1].z + xq.z * w[2].z + xq.w * w[3].z;
      acc[i].w += xq.x * w[0].w + xq.y * w[1].w + xq.z * w[2].w + xq.w * w[3].w;
    }
  }

#pragma unroll
  for (int i = 0; i < RI; ++i) {
    int r = rbase + rs + RS * i;
    if (r < M) *(float4*)&Y[r * NC + 4 * cg] = acc[i];
  }
}

// --- gather-style aggregation (atomic-free), fused self-loop + bias (+ReLU) ---
template <int NC, bool RELU>
__global__ __launch_bounds__(256) void agg_kernel(const float* __restrict__ H,
                                                  const int* __restrict__ row_start,
                                                  const int2* __restrict__ csr,
                                                  const float* __restrict__ dinv,
                                                  const float* __restrict__ bias,
                                                  float* __restrict__ OUT, int N) {
  constexpr int LPN = NC / 4;    // 32 or 16
  constexpr int NPB = 256 / LPN; // 8 or 16
  int t = threadIdx.x;
  int lane = t % LPN;
  int n = blockIdx.x * NPB + t / LPN;
  if (n >= N) return;

  int s0 = row_start[n];
  int s1 = row_start[n + 1];
  float4 acc = make_float4(0.f, 0.f, 0.f, 0.f);
  for (int j = s0; j < s1; ++j) {
    int2 sn = csr[j];
    int s = sn.x;
    float w = __int_as_float(sn.y);
    float4 h = *(const float4*)&H[s * NC + 4 * lane];
    acc.x += w * h.x; acc.y += w * h.y; acc.z += w * h.z; acc.w += w * h.w;
  }
  float di = dinv[n];
  float sw = di * di;
  float4 hs = *(const float4*)&H[n * NC + 4 * lane];
  float4 b  = *(const float4*)&bias[4 * lane];
  float4 o;
  o.x = acc.x + sw * hs.x + b.x;
  o.y = acc.y + sw * hs.y + b.y;
  o.z = acc.z + sw * hs.z + b.z;
  o.w = acc.w + sw * hs.w + b.w;
  if (RELU) {
    o.x = fmaxf(o.x, 0.f); o.y = fmaxf(o.y, 0.f);
    o.z = fmaxf(o.z, 0.f); o.w = fmaxf(o.w, 0.f);
  }
  *(float4*)&OUT[n * NC + 4 * lane] = o;
}

extern "C" void kernel_launch(void* const* d_in, const int* in_sizes, int n_in,
                              void* d_out, int out_size, void* d_ws, size_t ws_size,
                              hipStream_t stream) {
  const float* x  = (const float*)d_in[0];
  const int*   ei = (const int*)d_in[1];
  const float* ew = (const float*)d_in[2];
  const float* W1 = (const float*)d_in[3];
  const float* b1 = (const float*)d_in[4];
  const float* W2 = (const float*)d_in[5];
  const float* b2 = (const float*)d_in[6];
  float* out = (float*)d_out;

  const int IN_D = 128, HID = 128, OUT_D = 64;
  const int N = in_sizes[0] / IN_D;   // 50000
  const int E = in_sizes[2];          // 800000

  char* ws = (char*)d_ws;
  size_t off = 0;
  auto take = [&](size_t bytes) -> void* {
    void* p = ws + off;
    off += (bytes + 255) & ~(size_t)255;
    return p;
  };
  unsigned long long* packed = (unsigned long long*)take((size_t)N * 8);
  float* dinv      = (float*)take((size_t)N * 4);
  int*   cnt       = (int*)take((size_t)N * 4);
  int*   row_start = (int*)take((size_t)(N + 1) * 4);
  int*   bsum      = (int*)take(256 * 4);
  int*   flag      = (int*)take(256);
  unsigned short* rank = (unsigned short*)take((size_t)E * 2);
  int2*  csr       = (int2*)take((size_t)E * 8);
  float* h1        = (float*)take((size_t)N * HID * 4);
  float* h2        = (float*)take((size_t)N * HID * 4);
  float* h3        = (float*)take((size_t)N * OUT_D * 4);

  int nb_n = (N + 255) / 256;  // 196
  int nb_e = (E + 255) / 256;  // 3125
  int nb_g = (N + 63) / 64;    // 782

  hipLaunchKernelGGL(k_detect, dim3(1), dim3(256), 0, stream, ei, flag, E);
  hipLaunchKernelGGL(k_init, dim3(nb_n), dim3(256), 0, stream, packed, N);
  hipLaunchKernelGGL(k_hist2, dim3(nb_e), dim3(256), 0, stream, ei, ew, packed, rank, E, flag);
  hipLaunchKernelGGL(k_dinv_scan1, dim3(nb_n), dim3(256), 0, stream, packed, dinv, cnt, bsum, N);
  hipLaunchKernelGGL(k_scan2, dim3(1), dim3(256), 0, stream, bsum, row_start, nb_n, N, E);
  hipLaunchKernelGGL(k_scan3, dim3(nb_n), dim3(256), 0, stream, cnt, bsum, row_start, N);
  hipLaunchKernelGGL(k_fill2, dim3(nb_e), dim3(256), 0, stream, ei, ew, dinv, row_start,
                     rank, csr, E, flag);
  hipLaunchKernelGGL((gemm_kernel<128>), dim3(nb_g), dim3(256), 0, stream, x, W1, h1, N);
  hipLaunchKernelGGL((agg_kernel<128, true>), dim3((N + 7) / 8), dim3(256), 0, stream,
                     h1, row_start, csr, dinv, b1, h2, N);
  hipLaunchKernelGGL((gemm_kernel<64>), dim3(nb_g), dim3(256), 0, stream, h2, W2, h3, N);
  hipLaunchKernelGGL((agg_kernel<64, false>), dim3((N + 15) / 16), dim3(256), 0, stream,
                     h3, row_start, csr, dinv, b2, out, N);
}

// Round 4
// 319.766 us; speedup vs baseline: 1.2515x; 1.0460x over previous
//
#include <hip/hip_runtime.h>
#include <math.h>

// ---------------------------------------------------------------------------
// GCN 2-layer forward on MI355X.
// Round 3 (resubmit — round-3 bench never ran): 4-way unrolled gather loop in
// agg_kernel (4 independent CSR reads + 4 independent float4 gathers in
// flight per lane) to raise MLP — the round-2 profile showed agg
// latency-bound (VALUBusy 10%, 41% fabric BW).
// CSR build unchanged: one packed 64-bit atomic per edge
//   bits [40:63] = incoming-edge count, bits [0:39] = fixed-point wsum (2^-24)
// atomic return value -> edge rank -> atomic-free CSR fill of int2{src,norm}.
// ---------------------------------------------------------------------------

#define WFIX_SCALE 16777216.0f  // 2^24
#define WFIX_MASK  0xFFFFFFFFFFULL

// --- dtype detect: flag=1 if edge_index is int64 (all sampled high words 0) ---
__global__ __launch_bounds__(256) void k_detect(const int* __restrict__ ei,
                                                int* __restrict__ flagp, int E) {
  __shared__ int sm[256];
  int t = threadIdx.x;
  int v = 0;
#pragma unroll
  for (int j = 0; j < 8; ++j) {
    int e = t * 8 + j;           // e < 2048, safely inside both layouts
    if (2 * e + 1 < 2 * E) v |= ei[2 * e + 1];
  }
  sm[t] = v;
  __syncthreads();
  for (int off = 128; off > 0; off >>= 1) {
    if (t < off) sm[t] |= sm[t + off];
    __syncthreads();
  }
  if (t == 0) flagp[0] = (sm[0] == 0) ? 1 : 0;
}

__global__ __launch_bounds__(256) void k_init(unsigned long long* __restrict__ packed,
                                              int N) {
  int i = blockIdx.x * 256 + threadIdx.x;
  if (i < N) packed[i] = 0ULL;
}

// one packed 64-bit atomic per edge; returned old value -> rank within dst row
__global__ __launch_bounds__(256) void k_hist2(const int* __restrict__ ei,
                                               const float* __restrict__ ew,
                                               unsigned long long* __restrict__ packed,
                                               unsigned short* __restrict__ rank,
                                               int E, const int* __restrict__ flagp) {
  int e = blockIdx.x * 256 + threadIdx.x;
  if (e >= E) return;
  int is64 = flagp[0];
  int d = is64 ? ei[2 * E + 2 * e] : ei[E + e];
  unsigned long long wfix = (unsigned long long)(ew[e] * WFIX_SCALE + 0.5f);
  unsigned long long old = atomicAdd(&packed[d], wfix | (1ULL << 40));
  rank[e] = (unsigned short)(old >> 40);
}

// unpack: dinv = rsqrt(1 + wsum), cnt; and block-sum cnt for the scan
__global__ __launch_bounds__(256) void k_dinv_scan1(
    const unsigned long long* __restrict__ packed, float* __restrict__ dinv,
    int* __restrict__ cnt, int* __restrict__ bsum, int N) {
  __shared__ int sm[256];
  int t = threadIdx.x;
  int i = blockIdx.x * 256 + t;
  int c = 0;
  if (i < N) {
    unsigned long long p = packed[i];
    c = (int)(p >> 40);
    float deg = 1.0f + (float)(p & WFIX_MASK) * (1.0f / WFIX_SCALE);
    dinv[i] = rsqrtf(deg);
    cnt[i] = c;
  }
  sm[t] = c;
  __syncthreads();
  for (int off = 128; off > 0; off >>= 1) {
    if (t < off) sm[t] += sm[t + off];
    __syncthreads();
  }
  if (t == 0) bsum[blockIdx.x] = sm[0];
}

__global__ __launch_bounds__(256) void k_scan2(int* __restrict__ bsum,
                                               int* __restrict__ row_start,
                                               int NB, int N, int E) {
  __shared__ int sm[256];
  int t = threadIdx.x;
  int v = (t < NB) ? bsum[t] : 0;
  sm[t] = v;
  __syncthreads();
  for (int off = 1; off < 256; off <<= 1) {
    int add = (t >= off) ? sm[t - off] : 0;
    __syncthreads();
    sm[t] += add;
    __syncthreads();
  }
  if (t < NB) bsum[t] = sm[t] - v;  // exclusive block offsets
  if (t == 0) row_start[N] = E;
}

__global__ __launch_bounds__(256) void k_scan3(const int* __restrict__ cnt,
                                               const int* __restrict__ bsum,
                                               int* __restrict__ row_start, int N) {
  __shared__ int sm[256];
  int t = threadIdx.x;
  int i = blockIdx.x * 256 + t;
  int v = (i < N) ? cnt[i] : 0;
  sm[t] = v;
  __syncthreads();
  for (int off = 1; off < 256; off <<= 1) {
    int add = (t >= off) ? sm[t - off] : 0;
    __syncthreads();
    sm[t] += add;
    __syncthreads();
  }
  if (i < N) row_start[i] = sm[t] - v + bsum[blockIdx.x];
}

// CSR fill, atomic-free: pos = row_start[dst] + rank[e]; one packed int2 store
__global__ __launch_bounds__(256) void k_fill2(const int* __restrict__ ei,
                                               const float* __restrict__ ew,
                                               const float* __restrict__ dinv,
                                               const int* __restrict__ row_start,
                                               const unsigned short* __restrict__ rank,
                                               int2* __restrict__ csr, int E,
                                               const int* __restrict__ flagp) {
  int e = blockIdx.x * 256 + threadIdx.x;
  if (e >= E) return;
  int is64 = flagp[0];
  int s, d;
  if (is64) { s = ei[2 * e]; d = ei[2 * E + 2 * e]; }
  else      { s = ei[e];     d = ei[E + e]; }
  float nw = dinv[s] * ew[e] * dinv[d];
  int pos = row_start[d] + (int)rank[e];
  csr[pos] = make_int2(s, __float_as_int(nw));
}

// --- fp32 register-tiled GEMM: Y[M,NC] = X[M,128] @ W[128,NC] ---
template <int NC>
__global__ __launch_bounds__(256) void gemm_kernel(const float* __restrict__ X,
                                                   const float* __restrict__ W,
                                                   float* __restrict__ Y, int M) {
  constexpr int K = 128;
  constexpr int CG = NC / 4;    // col groups: 32 (NC=128) or 16 (NC=64)
  constexpr int RS = 256 / CG;  // row subs: 8 or 16
  constexpr int RI = 64 / RS;   // rows per thread: 8 or 4
  int t = threadIdx.x;
  int cg = t % CG;
  int rs = t / CG;
  int rbase = blockIdx.x * 64;

  float4 acc[RI];
#pragma unroll
  for (int i = 0; i < RI; ++i) acc[i] = make_float4(0.f, 0.f, 0.f, 0.f);

  int rows[RI];
#pragma unroll
  for (int i = 0; i < RI; ++i) {
    int r = rbase + rs + RS * i;
    rows[i] = (r < M) ? r : (M - 1);  // clamp loads, guard stores
  }

  for (int k0 = 0; k0 < K; k0 += 4) {
    float4 w[4];
#pragma unroll
    for (int j = 0; j < 4; ++j)
      w[j] = *(const float4*)&W[(k0 + j) * NC + 4 * cg];
#pragma unroll
    for (int i = 0; i < RI; ++i) {
      float4 xq = *(const float4*)&X[rows[i] * K + k0];
      acc[i].x += xq.x * w[0].x + xq.y * w[1].x + xq.z * w[2].x + xq.w * w[3].x;
      acc[i].y += xq.x * w[0].y + xq.y * w[1].y + xq.z * w[2].y + xq.w * w[3].y;
      acc[i].z += xq.x * w[0].z + xq.y * w[1].z + xq.z * w[2].z + xq.w * w[3].z;
      acc[i].w += xq.x * w[0].w + xq.y * w[1].w + xq.z * w[2].w + xq.w * w[3].w;
    }
  }

#pragma unroll
  for (int i = 0; i < RI; ++i) {
    int r = rbase + rs + RS * i;
    if (r < M) *(float4*)&Y[r * NC + 4 * cg] = acc[i];
  }
}

// --- gather-style aggregation (atomic-free), fused self-loop + bias (+ReLU) ---
// 4-way unrolled edge loop: 4 independent csr reads + 4 independent float4
// gathers in flight per lane -> ~4x MLP vs round-2's serial loop.
template <int NC, bool RELU>
__global__ __launch_bounds__(256) void agg_kernel(const float* __restrict__ H,
                                                  const int* __restrict__ row_start,
                                                  const int2* __restrict__ csr,
                                                  const float* __restrict__ dinv,
                                                  const float* __restrict__ bias,
                                                  float* __restrict__ OUT, int N) {
  constexpr int LPN = NC / 4;    // 32 or 16
  constexpr int NPB = 256 / LPN; // 8 or 16
  int t = threadIdx.x;
  int lane = t % LPN;
  int n = blockIdx.x * NPB + t / LPN;
  if (n >= N) return;

  int s0 = row_start[n];
  int s1 = row_start[n + 1];
  float4 acc = make_float4(0.f, 0.f, 0.f, 0.f);

  int j = s0;
  for (; j + 4 <= s1; j += 4) {
    int2 e0 = csr[j];
    int2 e1 = csr[j + 1];
    int2 e2 = csr[j + 2];
    int2 e3 = csr[j + 3];
    float4 h0 = *(const float4*)&H[(size_t)e0.x * NC + 4 * lane];
    float4 h1 = *(const float4*)&H[(size_t)e1.x * NC + 4 * lane];
    float4 h2 = *(const float4*)&H[(size_t)e2.x * NC + 4 * lane];
    float4 h3 = *(const float4*)&H[(size_t)e3.x * NC + 4 * lane];
    float w0 = __int_as_float(e0.y);
    float w1 = __int_as_float(e1.y);
    float w2 = __int_as_float(e2.y);
    float w3 = __int_as_float(e3.y);
    acc.x += w0 * h0.x + w1 * h1.x + w2 * h2.x + w3 * h3.x;
    acc.y += w0 * h0.y + w1 * h1.y + w2 * h2.y + w3 * h3.y;
    acc.z += w0 * h0.z + w1 * h1.z + w2 * h2.z + w3 * h3.z;
    acc.w += w0 * h0.w + w1 * h1.w + w2 * h2.w + w3 * h3.w;
  }
  for (; j < s1; ++j) {
    int2 sn = csr[j];
    float w = __int_as_float(sn.y);
    float4 h = *(const float4*)&H[(size_t)sn.x * NC + 4 * lane];
    acc.x += w * h.x; acc.y += w * h.y; acc.z += w * h.z; acc.w += w * h.w;
  }

  float di = dinv[n];
  float sw = di * di;
  float4 hs = *(const float4*)&H[(size_t)n * NC + 4 * lane];
  float4 b  = *(const float4*)&bias[4 * lane];
  float4 o;
  o.x = acc.x + sw * hs.x + b.x;
  o.y = acc.y + sw * hs.y + b.y;
  o.z = acc.z + sw * hs.z + b.z;
  o.w = acc.w + sw * hs.w + b.w;
  if (RELU) {
    o.x = fmaxf(o.x, 0.f); o.y = fmaxf(o.y, 0.f);
    o.z = fmaxf(o.z, 0.f); o.w = fmaxf(o.w, 0.f);
  }
  *(float4*)&OUT[(size_t)n * NC + 4 * lane] = o;
}

extern "C" void kernel_launch(void* const* d_in, const int* in_sizes, int n_in,
                              void* d_out, int out_size, void* d_ws, size_t ws_size,
                              hipStream_t stream) {
  const float* x  = (const float*)d_in[0];
  const int*   ei = (const int*)d_in[1];
  const float* ew = (const float*)d_in[2];
  const float* W1 = (const float*)d_in[3];
  const float* b1 = (const float*)d_in[4];
  const float* W2 = (const float*)d_in[5];
  const float* b2 = (const float*)d_in[6];
  float* out = (float*)d_out;

  const int IN_D = 128, HID = 128, OUT_D = 64;
  const int N = in_sizes[0] / IN_D;   // 50000
  const int E = in_sizes[2];          // 800000

  char* ws = (char*)d_ws;
  size_t off = 0;
  auto take = [&](size_t bytes) -> void* {
    void* p = ws + off;
    off += (bytes + 255) & ~(size_t)255;
    return p;
  };
  unsigned long long* packed = (unsigned long long*)take((size_t)N * 8);
  float* dinv      = (float*)take((size_t)N * 4);
  int*   cnt       = (int*)take((size_t)N * 4);
  int*   row_start = (int*)take((size_t)(N + 1) * 4);
  int*   bsum      = (int*)take(256 * 4);
  int*   flag      = (int*)take(256);
  unsigned short* rank = (unsigned short*)take((size_t)E * 2);
  int2*  csr       = (int2*)take((size_t)E * 8);
  float* h1        = (float*)take((size_t)N * HID * 4);
  float* h2        = (float*)take((size_t)N * HID * 4);
  float* h3        = (float*)take((size_t)N * OUT_D * 4);

  int nb_n = (N + 255) / 256;  // 196
  int nb_e = (E + 255) / 256;  // 3125
  int nb_g = (N + 63) / 64;    // 782

  hipLaunchKernelGGL(k_detect, dim3(1), dim3(256), 0, stream, ei, flag, E);
  hipLaunchKernelGGL(k_init, dim3(nb_n), dim3(256), 0, stream, packed, N);
  hipLaunchKernelGGL(k_hist2, dim3(nb_e), dim3(256), 0, stream, ei, ew, packed, rank, E, flag);
  hipLaunchKernelGGL(k_dinv_scan1, dim3(nb_n), dim3(256), 0, stream, packed, dinv, cnt, bsum, N);
  hipLaunchKernelGGL(k_scan2, dim3(1), dim3(256), 0, stream, bsum, row_start, nb_n, N, E);
  hipLaunchKernelGGL(k_scan3, dim3(nb_n), dim3(256), 0, stream, cnt, bsum, row_start, N);
  hipLaunchKernelGGL(k_fill2, dim3(nb_e), dim3(256), 0, stream, ei, ew, dinv, row_start,
                     rank, csr, E, flag);
  hipLaunchKernelGGL((gemm_kernel<128>), dim3(nb_g), dim3(256), 0, stream, x, W1, h1, N);
  hipLaunchKernelGGL((agg_kernel<128, true>), dim3((N + 7) / 8), dim3(256), 0, stream,
                     h1, row_start, csr, dinv, b1, h2, N);
  hipLaunchKernelGGL((gemm_kernel<64>), dim3(nb_g), dim3(256), 0, stream, h2, W2, h3, N);
  hipLaunchKernelGGL((agg_kernel<64, false>), dim3((N + 15) / 16), dim3(256), 0, stream,
                     h3, row_start, csr, dinv, b2, out, N);
}